// Round 12
// baseline (1470.819 us; speedup 1.0000x reference)
//
#include <hip/hip_runtime.h>

#define MDIM 8192
#define NDIM 16384
#define KDIM 4096

typedef __bf16 bf16x8 __attribute__((ext_vector_type(8)));
typedef float f32x4 __attribute__((ext_vector_type(4)));
typedef float f32x16 __attribute__((ext_vector_type(16)));

__device__ __forceinline__ unsigned short f2bf(float f) {
  __bf16 h = (__bf16)f;
  return __builtin_bit_cast(unsigned short, h);
}

__device__ __forceinline__ void gload_lds16(const void* g, void* l) {
  __builtin_amdgcn_global_load_lds(
      (const __attribute__((address_space(1))) unsigned int*)g,
      (__attribute__((address_space(3))) unsigned int*)l, 16, 0, 0);
}

// ======== ws layouts (ks-plane-major; all GEMM LDS traffic contiguous) ======
// Ab: [mtile(32)][kt32(128)][ks(4)][row(256)][8]  (== old [kt64][ks8] bytes)
// Wb: [ntile(64)][kt32(128)][ks(4)][row(256)][8]
// (ks = k/8 within the BK=32 tile; cell = 8 bf16 = 16B; 16KB per (tile,kt))

// ---------- pass 1a: fp32 -> bf16 into Ab (LDS-bounced transpose) ----------
__global__ __launch_bounds__(256) void cvt_a_kernel(const float* __restrict__ a,
                                                    unsigned short* __restrict__ o) {
  __shared__ unsigned short lds[4 * 2056];
  const int mt = blockIdx.x >> 7;
  const int kt = (blockIdx.x >> 1) & 63;
  const int kq = blockIdx.x & 1;
  const int tid = threadIdx.x;
#pragma unroll
  for (int j = 0; j < 8; ++j) {
    const int idx = tid + j * 256;
    const int row = idx >> 3;
    const int kc = idx & 7;
    float4 v = *(const float4*)(a + (long long)(mt * 256 + row) * KDIM +
                                kt * 64 + kq * 32 + kc * 4);
    ushort4 u;
    u.x = f2bf(v.x); u.y = f2bf(v.y); u.z = f2bf(v.z); u.w = f2bf(v.w);
    *(ushort4*)&lds[(kc >> 1) * 2056 + row * 8 + (kc & 1) * 4] = u;
  }
  __syncthreads();
  unsigned short* dst = o + (((long long)mt * 64 + kt) << 14) + (kq << 13);
#pragma unroll
  for (int j = 0; j < 4; ++j) {
    const int c = tid + j * 256;
    *(uint4*)(dst + c * 8) = *(const uint4*)&lds[(c >> 8) * 2056 + (c & 255) * 8];
  }
}

// ---------- pass 1b: int32 (int8 values) -> bf16 into Wb ----------
__global__ __launch_bounds__(256) void cvt_w_kernel(const int* __restrict__ w,
                                                    unsigned short* __restrict__ o) {
  __shared__ unsigned short lds[4 * 2056];
  const int nt = blockIdx.x >> 7;
  const int kt = (blockIdx.x >> 1) & 63;
  const int kq = blockIdx.x & 1;
  const int tid = threadIdx.x;
#pragma unroll
  for (int j = 0; j < 8; ++j) {
    const int idx = tid + j * 256;
    const int row = idx >> 3;
    const int kc = idx & 7;
    int4 v = *(const int4*)(w + (long long)(nt * 256 + row) * KDIM +
                            kt * 64 + kq * 32 + kc * 4);
    ushort4 u;
    u.x = f2bf((float)v.x); u.y = f2bf((float)v.y);
    u.z = f2bf((float)v.z); u.w = f2bf((float)v.w);
    *(ushort4*)&lds[(kc >> 1) * 2056 + row * 8 + (kc & 1) * 4] = u;
  }
  __syncthreads();
  unsigned short* dst = o + (((long long)nt * 64 + kt) << 14) + (kq << 13);
#pragma unroll
  for (int j = 0; j < 4; ++j) {
    const int c = tid + j * 256;
    *(uint4*)(dst + c * 8) = *(const uint4*)&lds[(c >> 8) * 2056 + (c & 255) * 8];
  }
}

// ---------- pass 2: 256x256 tile, BK=32, 4 waves x (128x128), 32x32x16 MFMA,
// 3-slot ring (96 KiB), counted vmcnt(8), 1 barrier/K-tile ----
// Read traffic cut 1.5x vs 8x(128x64): 64 wave-b128 per K-tile32 (the dominant
// serial term). acc = 16 f32x16 = 256 VGPR -> 256-thread block (cap 512/thr).
// Slot (32KB): A [ks4][row256][16B] at +0; B same at +16384.
// Ring: stage(t+2)->bS during t (bS = slot of t-1, freed at t-1's barrier);
// end-of-t gate vmcnt(8) leaves only stage(t+2)'s 8 in flight -> t+1 resident.
__global__ __launch_bounds__(256, 1) void gemm_bf16_v12(
    const unsigned short* __restrict__ Ab, const unsigned short* __restrict__ Wb,
    const float* __restrict__ sc, const float* __restrict__ bi,
    float* __restrict__ out) {
  __shared__ alignas(16) char sm[3 * 32768];
  const int tid = threadIdx.x;
  const int lane = tid & 63;
  const int wv = tid >> 6;   // 0..3
  const int l31 = lane & 31;
  const int l32 = lane >> 5;
  const int wr = wv >> 1;    // 0..1 -> rows wr*128
  const int wcn = wv & 1;    // 0..1 -> cols wcn*128
  // 2D XCD chunking (verified: FETCH ~0.8 GB): 2048 blocks
  const int c = blockIdx.x & 7;
  const int l = blockIdx.x >> 3;              // 0..255
  const int mA = ((c & 3) << 3) + (l & 7);    // 0..31
  const int nT = ((c >> 2) << 5) + (l >> 3);  // 0..63
  const int bm = mA << 8;
  const int bn = nT << 8;

  // frag byte-offsets (slot-relative); each read = 32 lanes x 16B contiguous
  int aO[2][4], bO[2][4];
#pragma unroll
  for (int kk = 0; kk < 2; ++kk) {
#pragma unroll
    for (int mb = 0; mb < 4; ++mb)
      aO[kk][mb] = (kk * 2 + l32) * 4096 + (wr * 128 + mb * 32 + l31) * 16;
#pragma unroll
    for (int nb = 0; nb < 4; ++nb)
      bO[kk][nb] = 16384 + (kk * 2 + l32) * 4096 + (wcn * 128 + nb * 32 + l31) * 16;
  }

  f32x16 acc[4][4] = {};

  const unsigned short* aSrc = Ab + (((long long)mA * 128) << 13) + (tid << 3);
  const unsigned short* bSrc = Wb + (((long long)nT * 128) << 13) + (tid << 3);
  const int t16 = tid << 4;

  char* bR = &sm[0];
  char* bN = &sm[32768];
  char* bS = &sm[65536];

  auto STAGE = [&](char* slot) {  // 8 gl_lds/thread = one 32KB K-tile
#pragma unroll
    for (int r = 0; r < 4; ++r)
      gload_lds16(aSrc + r * 2048, slot + t16 + r * 4096);
#pragma unroll
    for (int r = 0; r < 4; ++r)
      gload_lds16(bSrc + r * 2048, slot + 16384 + t16 + r * 4096);
    aSrc += 8192;
    bSrc += 8192;
  };

  // prologue: tiles 0,1; retire tile 0 (8 newest = tile 1 stay in flight)
  STAGE(bR);
  STAGE(bN);
  asm volatile("s_waitcnt vmcnt(8)" ::: "memory");
  __builtin_amdgcn_s_barrier();

  for (int t = 0; t < 128; ++t) {
    if (t <= 125) STAGE(bS);  // tile t+2 -> slot of t-1 (freed at t-1 barrier)
    __builtin_amdgcn_s_setprio(1);
    bf16x8 aF[2][4], bF[2][4];
#pragma unroll
    for (int kk = 0; kk < 2; ++kk) {
#pragma unroll
      for (int mb = 0; mb < 4; ++mb) aF[kk][mb] = *(const bf16x8*)(bR + aO[kk][mb]);
#pragma unroll
      for (int nb = 0; nb < 4; ++nb) bF[kk][nb] = *(const bf16x8*)(bR + bO[kk][nb]);
    }
#pragma unroll
    for (int kk = 0; kk < 2; ++kk)
#pragma unroll
      for (int mb = 0; mb < 4; ++mb)
#pragma unroll
        for (int nb = 0; nb < 4; ++nb)
          acc[mb][nb] = __builtin_amdgcn_mfma_f32_32x32x16_bf16(
              aF[kk][mb], bF[kk][nb], acc[mb][nb], 0, 0, 0);
    __builtin_amdgcn_s_setprio(0);
    if (t <= 125) {
      asm volatile("s_waitcnt vmcnt(8)" ::: "memory");  // tile t+1 resident
    } else if (t == 126) {
      asm volatile("s_waitcnt vmcnt(0)" ::: "memory");  // tile 127 resident
    }
    if (t < 127) __builtin_amdgcn_s_barrier();
    char* tmp = bR; bR = bN; bN = bS; bS = tmp;
  }

  // epilogue: 32x32 C/D layout col = lane&31, row = (r&3) + 8*(r>>2) + 4*l32
  float sv[4], bv[4];
#pragma unroll
  for (int nb = 0; nb < 4; ++nb) {
    const int cc = bn + wcn * 128 + nb * 32 + l31;
    sv[nb] = sc[cc];
    bv[nb] = bi[cc];
  }
#pragma unroll
  for (int mb = 0; mb < 4; ++mb) {
    const int rb = bm + wr * 128 + mb * 32 + l32 * 4;
#pragma unroll
    for (int nb = 0; nb < 4; ++nb) {
      const int cc = bn + wcn * 128 + nb * 32 + l31;
      const float s = sv[nb], b = bv[nb];
#pragma unroll
      for (int r = 0; r < 16; ++r) {
        const long long row = rb + (r & 3) + 8 * (r >> 2);
        __builtin_nontemporal_store(acc[mb][nb][r] * s + b, out + row * NDIM + cc);
      }
    }
  }
}

// ---------- fallback: inline-convert reg-staged GEMM (if ws too small) ----------
__global__ __launch_bounds__(256, 2) void gemm_inline(
    const float* __restrict__ A, const int* __restrict__ W,
    const float* __restrict__ sc, const float* __restrict__ bi,
    float* __restrict__ out) {
  __shared__ unsigned short As[128 * 72];
  __shared__ unsigned short Bs[128 * 72];
  const int tid = threadIdx.x;
  const int lane = tid & 63;
  const int wv = tid >> 6;
  const int wg = (blockIdx.x & 7) * 1024 + (blockIdx.x >> 3);
  const int bm = (wg & 63) * 128;
  const int bn = (wg >> 6) * 128;
  const int wr = (wv >> 1) * 64;
  const int wc = (wv & 1) * 64;
  const int r16 = lane & 15;
  const int g4 = lane >> 4;

  f32x4 acc[4][4] = {};

  const int srow = tid >> 4;
  const int sc4 = (tid & 15) << 2;
  const float* aPtr = A + (long long)(bm + srow) * KDIM + sc4;
  const int* wPtr = W + (long long)(bn + srow) * KDIM + sc4;

  for (int kt = 0; kt < KDIM; kt += 64) {
    float4 av[8];
    int4 wv4[8];
#pragma unroll
    for (int j = 0; j < 8; ++j)
      av[j] = *(const float4*)(aPtr + (long long)j * 16 * KDIM + kt);
#pragma unroll
    for (int j = 0; j < 8; ++j)
      wv4[j] = *(const int4*)(wPtr + (long long)j * 16 * KDIM + kt);
    __syncthreads();
#pragma unroll
    for (int j = 0; j < 8; ++j) {
      ushort4 u;
      u.x = f2bf(av[j].x); u.y = f2bf(av[j].y);
      u.z = f2bf(av[j].z); u.w = f2bf(av[j].w);
      *(ushort4*)&As[(srow + j * 16) * 72 + sc4] = u;
    }
#pragma unroll
    for (int j = 0; j < 8; ++j) {
      ushort4 u;
      u.x = f2bf((float)wv4[j].x); u.y = f2bf((float)wv4[j].y);
      u.z = f2bf((float)wv4[j].z); u.w = f2bf((float)wv4[j].w);
      *(ushort4*)&Bs[(srow + j * 16) * 72 + sc4] = u;
    }
    __syncthreads();
#pragma unroll
    for (int ks = 0; ks < 2; ++ks) {
      bf16x8 aF[4], bF[4];
      const int kofs = ks * 32 + g4 * 8;
#pragma unroll
      for (int m2 = 0; m2 < 4; ++m2)
        aF[m2] = *(const bf16x8*)&As[(wr + m2 * 16 + r16) * 72 + kofs];
#pragma unroll
      for (int n2 = 0; n2 < 4; ++n2)
        bF[n2] = *(const bf16x8*)&Bs[(wc + n2 * 16 + r16) * 72 + kofs];
#pragma unroll
      for (int m2 = 0; m2 < 4; ++m2)
#pragma unroll
        for (int n2 = 0; n2 < 4; ++n2)
          acc[m2][n2] = __builtin_amdgcn_mfma_f32_16x16x32_bf16(
              aF[m2], bF[n2], acc[m2][n2], 0, 0, 0);
    }
  }

  float sv[4], bv[4];
#pragma unroll
  for (int n2 = 0; n2 < 4; ++n2) {
    const int c = bn + wc + n2 * 16 + r16;
    sv[n2] = sc[c];
    bv[n2] = bi[c];
  }
#pragma unroll
  for (int m2 = 0; m2 < 4; ++m2) {
    const int row0 = bm + wr + m2 * 16 + g4 * 4;
#pragma unroll
    for (int n2 = 0; n2 < 4; ++n2) {
      const int c = bn + wc + n2 * 16 + r16;
      float* op = out + (long long)row0 * NDIM + c;
#pragma unroll
      for (int r = 0; r < 4; ++r)
        op[(long long)r * NDIM] = acc[m2][n2][r] * sv[n2] + bv[n2];
    }
  }
}

extern "C" void kernel_launch(void* const* d_in, const int* in_sizes, int n_in,
                              void* d_out, int out_size, void* d_ws, size_t ws_size,
                              hipStream_t stream) {
  const float* A = (const float*)d_in[0];
  const int* W = (const int*)d_in[1];
  const float* sc = (const float*)d_in[2];
  const float* bi = (const float*)d_in[3];
  float* out = (float*)d_out;

  const long long nA = (long long)MDIM * KDIM;
  const long long nW = (long long)NDIM * KDIM;
  const size_t needA = (size_t)nA * sizeof(unsigned short);
  const size_t needW = (size_t)nW * sizeof(unsigned short);

  if (d_ws != nullptr && ws_size >= needA + needW) {
    unsigned short* Ab = (unsigned short*)d_ws;
    unsigned short* Wb = (unsigned short*)((char*)d_ws + needA);
    cvt_a_kernel<<<4096, 256, 0, stream>>>(A, Ab);
    cvt_w_kernel<<<8192, 256, 0, stream>>>(W, Wb);
    gemm_bf16_v12<<<2048, 256, 0, stream>>>(Ab, Wb, sc, bi, out);
  } else {
    gemm_inline<<<8192, 256, 0, stream>>>(A, W, sc, bi, out);
  }
}

// Round 13
// 656.727 us; speedup vs baseline: 2.2396x; 2.2396x over previous
//
#include <hip/hip_runtime.h>

#define MDIM 8192
#define NDIM 16384
#define KDIM 4096

typedef int i32x4 __attribute__((ext_vector_type(4)));
typedef int i32x16 __attribute__((ext_vector_type(16)));
typedef float f32x4 __attribute__((ext_vector_type(4)));

__device__ __forceinline__ unsigned short f2bf(float f) {
  __bf16 h = (__bf16)f;
  return __builtin_bit_cast(unsigned short, h);
}

__device__ __forceinline__ void gload_lds16(const void* g, void* l) {
  __builtin_amdgcn_global_load_lds(
      (const __attribute__((address_space(1))) unsigned int*)g,
      (__attribute__((address_space(3))) unsigned int*)l, 16, 0, 0);
}

// ======== int8 ws layouts (ks-plane-major, 16B cells; LDS traffic contiguous)
// Ab: [mtile(32)][kt64(64)][ks(4)][row(256)][16]  -> 16KB per (mtile,kt)
// Wb: [ntile(64)][kt64(64)][ks(4)][row(256)][16]
// cell (ks,row) holds k = kt*64 + ks*16 .. +16 of that row. sA: 8192 floats.

// ---------- pass 1a: dynamic per-row quantization A fp32 -> int8 ----------
__global__ __launch_bounds__(256) void cvt_a_q8(const float* __restrict__ a,
                                                signed char* __restrict__ o,
                                                float* __restrict__ sA) {
  const int row = blockIdx.x;  // 0..8191
  const int tid = threadIdx.x;
  float v[16];
  const float4* s4 = (const float4*)(a + (long long)row * KDIM + tid * 16);
#pragma unroll
  for (int i = 0; i < 4; ++i) {
    float4 f = s4[i];
    v[i * 4 + 0] = f.x; v[i * 4 + 1] = f.y;
    v[i * 4 + 2] = f.z; v[i * 4 + 3] = f.w;
  }
  float m = 0.f;
#pragma unroll
  for (int i = 0; i < 16; ++i) m = fmaxf(m, fabsf(v[i]));
#pragma unroll
  for (int off = 32; off; off >>= 1) m = fmaxf(m, __shfl_xor(m, off));
  __shared__ float red[4];
  if ((tid & 63) == 0) red[tid >> 6] = m;
  __syncthreads();
  m = fmaxf(fmaxf(red[0], red[1]), fmaxf(red[2], red[3]));
  const float inv = m > 0.f ? 127.f / m : 0.f;
  if (tid == 0) sA[row] = m * (1.f / 127.f);
  union { signed char c[16]; uint4 u; } p;
#pragma unroll
  for (int i = 0; i < 16; ++i)
    p.c[i] = (signed char)__float2int_rn(v[i] * inv);  // |v*inv| <= 127
  const int kt = tid >> 2, ks = tid & 3;
  *(uint4*)(o + ((((long long)(row >> 8) * 64 + kt) * 4 + ks) << 12) +
            ((row & 255) << 4)) = p.u;
}

// ---------- pass 1b: W int32 (int8 values, exact) -> int8 tile-panel --------
__global__ __launch_bounds__(256) void cvt_w_q8(const int* __restrict__ w,
                                                signed char* __restrict__ o) {
  const int nt = blockIdx.x >> 6;
  const int kt = blockIdx.x & 63;
  const int t = threadIdx.x;  // row (output channel within panel)
  const int* src = w + (long long)(nt * 256 + t) * KDIM + kt * 64;
  signed char* dst = o + (((long long)(nt * 64 + kt) * 4) << 12) + (t << 4);
#pragma unroll
  for (int ks = 0; ks < 4; ++ks) {
    union { signed char c[16]; uint4 u; } p;
#pragma unroll
    for (int i = 0; i < 4; ++i) {
      int4 x = *(const int4*)(src + ks * 16 + i * 4);
      p.c[i * 4 + 0] = (signed char)x.x; p.c[i * 4 + 1] = (signed char)x.y;
      p.c[i * 4 + 2] = (signed char)x.z; p.c[i * 4 + 3] = (signed char)x.w;
    }
    *(uint4*)(dst + (ks << 12)) = p.u;
  }
}

// ---------- pass 2: int8 GEMM, 256x256 tile, BK=64, 8 waves x (128x64),
// mfma_i32_32x32x32_i8, 3-slot ring (96 KiB), counted vmcnt(4) ----
// Slot (32KB): A [ks4][row256][16] at +0; B same at +16384.
// A frag: row = wr*128+mb*32+(lane&31), k-chunk = kk*32+(lane>>5)*16 (16 i8 =
// 4 VGPRs) -> plane kk*2+l32, contiguous 32-lane x 16B read (conflict-free).
// Ring: during t stage tile t+2 into slot of t-1 (freed at t-1 barrier);
// gate vmcnt(4) retires tile t+1 (only t+2's 4 loads stay in flight).
__global__ __launch_bounds__(512, 2) void gemm_i8_v13(
    const signed char* __restrict__ Ab, const signed char* __restrict__ Wb,
    const float* __restrict__ sA, const float* __restrict__ sc,
    const float* __restrict__ bi, float* __restrict__ out) {
  __shared__ alignas(16) char sm[3 * 32768];
  const int tid = threadIdx.x;
  const int lane = tid & 63;
  const int wv = tid >> 6;
  const int l31 = lane & 31;
  const int l32 = lane >> 5;
  const int wr = wv >> 2;   // 0..1 -> rows wr*128
  const int wc = wv & 3;    // 0..3 -> cols wc*64
  // 2D XCD chunking (verified: low FETCH)
  const int c = blockIdx.x & 7;
  const int l = blockIdx.x >> 3;              // 0..255
  const int mA = ((c & 3) << 3) + (l & 7);    // 0..31
  const int nT = ((c >> 2) << 5) + (l >> 3);  // 0..63
  const int bm = mA << 8;
  const int bn = nT << 8;

  int aO[2][4], bO[2][2];
#pragma unroll
  for (int kk = 0; kk < 2; ++kk) {
#pragma unroll
    for (int mb = 0; mb < 4; ++mb)
      aO[kk][mb] = (kk * 2 + l32) * 4096 + (wr * 128 + mb * 32 + l31) * 16;
#pragma unroll
    for (int nb = 0; nb < 2; ++nb)
      bO[kk][nb] = 16384 + (kk * 2 + l32) * 4096 + (wc * 64 + nb * 32 + l31) * 16;
  }

  i32x16 acc[4][2] = {};

  const signed char* aSrc = Ab + ((long long)mA << 20) + (tid << 4);
  const signed char* bSrc = Wb + ((long long)nT << 20) + (tid << 4);
  const int t16 = tid << 4;

  char* bR = &sm[0];
  char* bN = &sm[32768];
  char* bS = &sm[65536];

  auto STAGE = [&](char* slot) {  // 4 gl_lds/thread = one 32KB K-tile (A+B)
    gload_lds16(aSrc, slot + t16);
    gload_lds16(aSrc + 8192, slot + 8192 + t16);
    gload_lds16(bSrc, slot + 16384 + t16);
    gload_lds16(bSrc + 8192, slot + 24576 + t16);
    aSrc += 16384;
    bSrc += 16384;
  };

  // prologue: tiles 0,1; vmcnt(4) retires tile 0 (tile 1's 4 stay in flight)
  STAGE(bR);
  STAGE(bN);
  asm volatile("s_waitcnt vmcnt(4)" ::: "memory");
  __builtin_amdgcn_s_barrier();

  for (int t = 0; t < 64; ++t) {
    if (t <= 61) STAGE(bS);  // tile t+2 -> slot of t-1 (freed at t-1 barrier)
    __builtin_amdgcn_s_setprio(1);
    i32x4 aF[2][4], bF[2][2];
#pragma unroll
    for (int kk = 0; kk < 2; ++kk) {
#pragma unroll
      for (int mb = 0; mb < 4; ++mb) aF[kk][mb] = *(const i32x4*)(bR + aO[kk][mb]);
#pragma unroll
      for (int nb = 0; nb < 2; ++nb) bF[kk][nb] = *(const i32x4*)(bR + bO[kk][nb]);
    }
#pragma unroll
    for (int kk = 0; kk < 2; ++kk)
#pragma unroll
      for (int mb = 0; mb < 4; ++mb)
#pragma unroll
        for (int nb = 0; nb < 2; ++nb)
          acc[mb][nb] = __builtin_amdgcn_mfma_i32_32x32x32_i8(
              aF[kk][mb], bF[kk][nb], acc[mb][nb], 0, 0, 0);
    __builtin_amdgcn_s_setprio(0);
    if (t <= 61) {
      asm volatile("s_waitcnt vmcnt(4)" ::: "memory");  // tile t+1 resident
    } else if (t == 62) {
      asm volatile("s_waitcnt vmcnt(0)" ::: "memory");  // tile 63 resident
    }
    if (t < 63) __builtin_amdgcn_s_barrier();
    char* tmp = bR; bR = bN; bN = bS; bS = tmp;
  }

  // epilogue: out = acc * sA[row]*scale[col] + bias[col]
  // 32x32 C/D layout: col = lane&31, row = (r&3) + 8*(r>>2) + 4*l32
  float sv[2], bv[2];
#pragma unroll
  for (int nb = 0; nb < 2; ++nb) {
    const int cc = bn + wc * 64 + nb * 32 + l31;
    sv[nb] = sc[cc];
    bv[nb] = bi[cc];
  }
#pragma unroll
  for (int mb = 0; mb < 4; ++mb) {
    const int rb = bm + wr * 128 + mb * 32 + l32 * 4;
    float sa[16];
#pragma unroll
    for (int r = 0; r < 16; ++r) sa[r] = sA[rb + (r & 3) + 8 * (r >> 2)];
#pragma unroll
    for (int nb = 0; nb < 2; ++nb) {
      const int cc = bn + wc * 64 + nb * 32 + l31;
#pragma unroll
      for (int r = 0; r < 16; ++r) {
        const long long row = rb + (r & 3) + 8 * (r >> 2);
        __builtin_nontemporal_store(
            (float)acc[mb][nb][r] * (sa[r] * sv[nb]) + bv[nb],
            out + row * NDIM + cc);
      }
    }
  }
}

// ---------- fallback: inline-convert reg-staged bf16 GEMM (if ws too small) ----
__global__ __launch_bounds__(256, 2) void gemm_inline(
    const float* __restrict__ A, const int* __restrict__ W,
    const float* __restrict__ sc, const float* __restrict__ bi,
    float* __restrict__ out) {
  typedef __bf16 bf16x8 __attribute__((ext_vector_type(8)));
  __shared__ unsigned short As[128 * 72];
  __shared__ unsigned short Bs[128 * 72];
  const int tid = threadIdx.x;
  const int lane = tid & 63;
  const int wv = tid >> 6;
  const int wg = (blockIdx.x & 7) * 1024 + (blockIdx.x >> 3);
  const int bm = (wg & 63) * 128;
  const int bn = (wg >> 6) * 128;
  const int wr = (wv >> 1) * 64;
  const int wc = (wv & 1) * 64;
  const int r16 = lane & 15;
  const int g4 = lane >> 4;

  f32x4 acc[4][4] = {};

  const int srow = tid >> 4;
  const int sc4 = (tid & 15) << 2;
  const float* aPtr = A + (long long)(bm + srow) * KDIM + sc4;
  const int* wPtr = W + (long long)(bn + srow) * KDIM + sc4;

  for (int kt = 0; kt < KDIM; kt += 64) {
    float4 av[8];
    int4 wv4[8];
#pragma unroll
    for (int j = 0; j < 8; ++j)
      av[j] = *(const float4*)(aPtr + (long long)j * 16 * KDIM + kt);
#pragma unroll
    for (int j = 0; j < 8; ++j)
      wv4[j] = *(const int4*)(wPtr + (long long)j * 16 * KDIM + kt);
    __syncthreads();
#pragma unroll
    for (int j = 0; j < 8; ++j) {
      ushort4 u;
      u.x = f2bf(av[j].x); u.y = f2bf(av[j].y);
      u.z = f2bf(av[j].z); u.w = f2bf(av[j].w);
      *(ushort4*)&As[(srow + j * 16) * 72 + sc4] = u;
    }
#pragma unroll
    for (int j = 0; j < 8; ++j) {
      ushort4 u;
      u.x = f2bf((float)wv4[j].x); u.y = f2bf((float)wv4[j].y);
      u.z = f2bf((float)wv4[j].z); u.w = f2bf((float)wv4[j].w);
      *(ushort4*)&Bs[(srow + j * 16) * 72 + sc4] = u;
    }
    __syncthreads();
#pragma unroll
    for (int ks = 0; ks < 2; ++ks) {
      bf16x8 aF[4], bF[4];
      const int kofs = ks * 32 + g4 * 8;
#pragma unroll
      for (int m2 = 0; m2 < 4; ++m2)
        aF[m2] = *(const bf16x8*)&As[(wr + m2 * 16 + r16) * 72 + kofs];
#pragma unroll
      for (int n2 = 0; n2 < 4; ++n2)
        bF[n2] = *(const bf16x8*)&Bs[(wc + n2 * 16 + r16) * 72 + kofs];
#pragma unroll
      for (int m2 = 0; m2 < 4; ++m2)
#pragma unroll
        for (int n2 = 0; n2 < 4; ++n2)
          acc[m2][n2] = __builtin_amdgcn_mfma_f32_16x16x32_bf16(
              aF[m2], bF[n2], acc[m2][n2], 0, 0, 0);
    }
  }

  float sv[4], bv[4];
#pragma unroll
  for (int n2 = 0; n2 < 4; ++n2) {
    const int c = bn + wc + n2 * 16 + r16;
    sv[n2] = sc[c];
    bv[n2] = bi[c];
  }
#pragma unroll
  for (int m2 = 0; m2 < 4; ++m2) {
    const int row0 = bm + wr + m2 * 16 + g4 * 4;
#pragma unroll
    for (int n2 = 0; n2 < 4; ++n2) {
      const int c = bn + wc + n2 * 16 + r16;
      float* op = out + (long long)row0 * NDIM + c;
#pragma unroll
      for (int r = 0; r < 4; ++r)
        op[(long long)r * NDIM] = acc[m2][n2][r] * sv[n2] + bv[n2];
    }
  }
}

extern "C" void kernel_launch(void* const* d_in, const int* in_sizes, int n_in,
                              void* d_out, int out_size, void* d_ws, size_t ws_size,
                              hipStream_t stream) {
  const float* A = (const float*)d_in[0];
  const int* W = (const int*)d_in[1];
  const float* sc = (const float*)d_in[2];
  const float* bi = (const float*)d_in[3];
  float* out = (float*)d_out;

  const size_t needA = (size_t)MDIM * KDIM;          // int8: 32 MB
  const size_t needW = (size_t)NDIM * KDIM;          // int8: 64 MB
  const size_t offS = needA + needW;                 // 96 MB
  const size_t need = offS + (size_t)MDIM * 4;       // + sA

  if (d_ws != nullptr && ws_size >= need) {
    signed char* Ab = (signed char*)d_ws;
    signed char* Wb = (signed char*)d_ws + needA;
    float* sA = (float*)((char*)d_ws + offS);
    cvt_a_q8<<<8192, 256, 0, stream>>>(A, Ab, sA);
    cvt_w_q8<<<4096, 256, 0, stream>>>(W, Wb);
    gemm_i8_v13<<<2048, 512, 0, stream>>>(Ab, Wb, sA, sc, bi, out);
  } else {
    gemm_inline<<<8192, 256, 0, stream>>>(A, W, sc, bi, out);
  }
}

// Round 14
// 645.128 us; speedup vs baseline: 2.2799x; 1.0180x over previous
//
#include <hip/hip_runtime.h>

#define MDIM 8192
#define NDIM 16384
#define KDIM 4096

typedef int i32x4 __attribute__((ext_vector_type(4)));
typedef int i32x16 __attribute__((ext_vector_type(16)));
typedef float f32x4 __attribute__((ext_vector_type(4)));

__device__ __forceinline__ unsigned short f2bf(float f) {
  __bf16 h = (__bf16)f;
  return __builtin_bit_cast(unsigned short, h);
}

__device__ __forceinline__ void gload_lds16(const void* g, void* l) {
  __builtin_amdgcn_global_load_lds(
      (const __attribute__((address_space(1))) unsigned int*)g,
      (__attribute__((address_space(3))) unsigned int*)l, 16, 0, 0);
}

// ======== int8 ws layouts (ks-plane-major, 16B cells; LDS traffic contiguous)
// Ab: [mtile(32)][kt64(64)][ks(4)][row(256)][16]  -> 16KB per (mtile,kt)
// Wb: [ntile(64)][kt64(64)][ks(4)][row(256)][16]
// cell (ks,row) holds k = kt*64 + ks*16 .. +16 of that row. sA: 8192 floats.

// ---------- pass 1a: dynamic per-row quantization A fp32 -> int8 ----------
__global__ __launch_bounds__(256) void cvt_a_q8(const float* __restrict__ a,
                                                signed char* __restrict__ o,
                                                float* __restrict__ sA) {
  const int row = blockIdx.x;  // 0..8191
  const int tid = threadIdx.x;
  float v[16];
  const float4* s4 = (const float4*)(a + (long long)row * KDIM + tid * 16);
#pragma unroll
  for (int i = 0; i < 4; ++i) {
    float4 f = s4[i];
    v[i * 4 + 0] = f.x; v[i * 4 + 1] = f.y;
    v[i * 4 + 2] = f.z; v[i * 4 + 3] = f.w;
  }
  float m = 0.f;
#pragma unroll
  for (int i = 0; i < 16; ++i) m = fmaxf(m, fabsf(v[i]));
#pragma unroll
  for (int off = 32; off; off >>= 1) m = fmaxf(m, __shfl_xor(m, off));
  __shared__ float red[4];
  if ((tid & 63) == 0) red[tid >> 6] = m;
  __syncthreads();
  m = fmaxf(fmaxf(red[0], red[1]), fmaxf(red[2], red[3]));
  const float inv = m > 0.f ? 127.f / m : 0.f;
  if (tid == 0) sA[row] = m * (1.f / 127.f);
  union { signed char c[16]; uint4 u; } p;
#pragma unroll
  for (int i = 0; i < 16; ++i)
    p.c[i] = (signed char)__float2int_rn(v[i] * inv);  // |v*inv| <= 127
  const int kt = tid >> 2, ks = tid & 3;
  *(uint4*)(o + ((((long long)(row >> 8) * 64 + kt) * 4 + ks) << 12) +
            ((row & 255) << 4)) = p.u;
}

// ---------- pass 1b: W int32 (int8 values, exact) -> int8 tile-panel --------
__global__ __launch_bounds__(256) void cvt_w_q8(const int* __restrict__ w,
                                                signed char* __restrict__ o) {
  const int nt = blockIdx.x >> 6;
  const int kt = blockIdx.x & 63;
  const int t = threadIdx.x;  // row (output channel within panel)
  const int* src = w + (long long)(nt * 256 + t) * KDIM + kt * 64;
  signed char* dst = o + (((long long)(nt * 64 + kt) * 4) << 12) + (t << 4);
#pragma unroll
  for (int ks = 0; ks < 4; ++ks) {
    union { signed char c[16]; uint4 u; } p;
#pragma unroll
    for (int i = 0; i < 4; ++i) {
      int4 x = *(const int4*)(src + ks * 16 + i * 4);
      p.c[i * 4 + 0] = (signed char)x.x; p.c[i * 4 + 1] = (signed char)x.y;
      p.c[i * 4 + 2] = (signed char)x.z; p.c[i * 4 + 3] = (signed char)x.w;
    }
    *(uint4*)(dst + (ks << 12)) = p.u;
  }
}

// ---------- pass 2: int8 GEMM, 256x256, BK=64, 8 waves x (128x64),
// mfma_i32_32x32x32_i8, 4-slot ring (128 KiB), ONE sync per 2 K-tiles ----
// Pair p (tiles 2p,2p+1): STAGE(2p+2),(2p+3) -> slots read in pair p-1
// (behind its barrier, WAR-safe); LOADF+MFMA 2p; LOADF+MFMA 2p+1 (both tiles
// published by pair p-1's gate+barrier, RAW-safe); vmcnt(0) [stages have a
// full-pair ~4000cyc flight -> drain is free]; barrier. No volatile asm inside
// the window -> compiler may pipeline tile-(2p+1) ds_reads under tile-2p
// MFMAs, and waves drift a full tile between barriers.
__global__ __launch_bounds__(512, 2) void gemm_i8_v14(
    const signed char* __restrict__ Ab, const signed char* __restrict__ Wb,
    const float* __restrict__ sA, const float* __restrict__ sc,
    const float* __restrict__ bi, float* __restrict__ out) {
  __shared__ alignas(16) char sm[4 * 32768];
  const int tid = threadIdx.x;
  const int lane = tid & 63;
  const int wv = tid >> 6;
  const int l31 = lane & 31;
  const int l32 = lane >> 5;
  const int wr = wv >> 2;   // 0..1 -> rows wr*128
  const int wc = wv & 3;    // 0..3 -> cols wc*64
  // 2D XCD chunking (verified: low FETCH)
  const int c = blockIdx.x & 7;
  const int l = blockIdx.x >> 3;              // 0..255
  const int mA = ((c & 3) << 3) + (l & 7);    // 0..31
  const int nT = ((c >> 2) << 5) + (l >> 3);  // 0..63
  const int bm = mA << 8;
  const int bn = nT << 8;

  int aO[2][4], bO[2][2];
#pragma unroll
  for (int kk = 0; kk < 2; ++kk) {
#pragma unroll
    for (int mb = 0; mb < 4; ++mb)
      aO[kk][mb] = (kk * 2 + l32) * 4096 + (wr * 128 + mb * 32 + l31) * 16;
#pragma unroll
    for (int nb = 0; nb < 2; ++nb)
      bO[kk][nb] = 16384 + (kk * 2 + l32) * 4096 + (wc * 64 + nb * 32 + l31) * 16;
  }

  i32x16 acc[4][2] = {};

  const signed char* aSrc = Ab + ((long long)mA << 20) + (tid << 4);
  const signed char* bSrc = Wb + ((long long)nT << 20) + (tid << 4);
  const int t16 = tid << 4;

  char* const S0 = sm;
  char* const S1 = sm + 32768;
  char* const S2 = sm + 65536;
  char* const S3 = sm + 98304;

  auto STAGE = [&](char* slot) {  // 4 gl_lds/thread = one 32KB K-tile (A+B)
    gload_lds16(aSrc, slot + t16);
    gload_lds16(aSrc + 8192, slot + 8192 + t16);
    gload_lds16(bSrc, slot + 16384 + t16);
    gload_lds16(bSrc + 8192, slot + 24576 + t16);
    aSrc += 16384;
    bSrc += 16384;
  };

  auto TILE = [&](const char* slot) {  // reads + MFMAs for one K-tile64
    i32x4 aF[2][4], bF[2][2];
#pragma unroll
    for (int kk = 0; kk < 2; ++kk) {
#pragma unroll
      for (int mb = 0; mb < 4; ++mb)
        aF[kk][mb] = *(const i32x4*)(slot + aO[kk][mb]);
#pragma unroll
      for (int nb = 0; nb < 2; ++nb)
        bF[kk][nb] = *(const i32x4*)(slot + bO[kk][nb]);
    }
    __builtin_amdgcn_s_setprio(1);
#pragma unroll
    for (int kk = 0; kk < 2; ++kk)
#pragma unroll
      for (int mb = 0; mb < 4; ++mb)
#pragma unroll
        for (int nb = 0; nb < 2; ++nb)
          acc[mb][nb] = __builtin_amdgcn_mfma_i32_32x32x32_i8(
              aF[kk][mb], bF[kk][nb], acc[mb][nb], 0, 0, 0);
    __builtin_amdgcn_s_setprio(0);
  };

  // prologue: stage pair-0's tiles (0,1); publish.
  STAGE(S0);
  STAGE(S1);
  asm volatile("s_waitcnt vmcnt(0)" ::: "memory");
  __builtin_amdgcn_s_barrier();

#define PAIRF(sE, sO, tE, tO)                              \
  STAGE(tE);                                               \
  STAGE(tO);                                               \
  TILE(sE);                                                \
  TILE(sO);                                                \
  asm volatile("s_waitcnt vmcnt(0)" ::: "memory");         \
  __builtin_amdgcn_s_barrier();

  for (int i = 0; i < 15; ++i) {  // pairs 0..29 (tiles 0..59)
    PAIRF(S0, S1, S2, S3)
    PAIRF(S2, S3, S0, S1)
  }
  PAIRF(S0, S1, S2, S3)  // pair 30: tiles 60,61; stages 62,63
#undef PAIRF
  // pair 31: tiles 62,63; no stage, no gate
  TILE(S2);
  TILE(S3);

  // epilogue: out = acc * sA[row]*scale[col] + bias[col]
  // 32x32 C/D layout: col = lane&31, row = (r&3) + 8*(r>>2) + 4*l32
  float sv[2], bv[2];
#pragma unroll
  for (int nb = 0; nb < 2; ++nb) {
    const int cc = bn + wc * 64 + nb * 32 + l31;
    sv[nb] = sc[cc];
    bv[nb] = bi[cc];
  }
#pragma unroll
  for (int mb = 0; mb < 4; ++mb) {
    const int rb = bm + wr * 128 + mb * 32 + l32 * 4;
    float sa[16];
#pragma unroll
    for (int r = 0; r < 16; ++r) sa[r] = sA[rb + (r & 3) + 8 * (r >> 2)];
#pragma unroll
    for (int nb = 0; nb < 2; ++nb) {
      const int cc = bn + wc * 64 + nb * 32 + l31;
#pragma unroll
      for (int r = 0; r < 16; ++r) {
        const long long row = rb + (r & 3) + 8 * (r >> 2);
        __builtin_nontemporal_store(
            (float)acc[mb][nb][r] * (sa[r] * sv[nb]) + bv[nb],
            out + row * NDIM + cc);
      }
    }
  }
}

// ---------- fallback: inline-convert reg-staged bf16 GEMM (if ws too small) ----
__global__ __launch_bounds__(256, 2) void gemm_inline(
    const float* __restrict__ A, const int* __restrict__ W,
    const float* __restrict__ sc, const float* __restrict__ bi,
    float* __restrict__ out) {
  typedef __bf16 bf16x8 __attribute__((ext_vector_type(8)));
  __shared__ unsigned short As[128 * 72];
  __shared__ unsigned short Bs[128 * 72];
  const int tid = threadIdx.x;
  const int lane = tid & 63;
  const int wv = tid >> 6;
  const int wg = (blockIdx.x & 7) * 1024 + (blockIdx.x >> 3);
  const int bm = (wg & 63) * 128;
  const int bn = (wg >> 6) * 128;
  const int wr = (wv >> 1) * 64;
  const int wc = (wv & 1) * 64;
  const int r16 = lane & 15;
  const int g4 = lane >> 4;

  f32x4 acc[4][4] = {};

  const int srow = tid >> 4;
  const int sc4 = (tid & 15) << 2;
  const float* aPtr = A + (long long)(bm + srow) * KDIM + sc4;
  const int* wPtr = W + (long long)(bn + srow) * KDIM + sc4;

  for (int kt = 0; kt < KDIM; kt += 64) {
    float4 av[8];
    int4 wv4[8];
#pragma unroll
    for (int j = 0; j < 8; ++j)
      av[j] = *(const float4*)(aPtr + (long long)j * 16 * KDIM + kt);
#pragma unroll
    for (int j = 0; j < 8; ++j)
      wv4[j] = *(const int4*)(wPtr + (long long)j * 16 * KDIM + kt);
    __syncthreads();
#pragma unroll
    for (int j = 0; j < 8; ++j) {
      ushort4 u;
      u.x = f2bf(av[j].x); u.y = f2bf(av[j].y);
      u.z = f2bf(av[j].z); u.w = f2bf(av[j].w);
      *(ushort4*)&As[(srow + j * 16) * 72 + sc4] = u;
    }
#pragma unroll
    for (int j = 0; j < 8; ++j) {
      ushort4 u;
      u.x = f2bf((float)wv4[j].x); u.y = f2bf((float)wv4[j].y);
      u.z = f2bf((float)wv4[j].z); u.w = f2bf((float)wv4[j].w);
      *(ushort4*)&Bs[(srow + j * 16) * 72 + sc4] = u;
    }
    __syncthreads();
#pragma unroll
    for (int ks = 0; ks < 2; ++ks) {
      bf16x8 aF[4], bF[4];
      const int kofs = ks * 32 + g4 * 8;
#pragma unroll
      for (int m2 = 0; m2 < 4; ++m2)
        aF[m2] = *(const bf16x8*)&As[(wr + m2 * 16 + r16) * 72 + kofs];
#pragma unroll
      for (int n2 = 0; n2 < 4; ++n2)
        bF[n2] = *(const bf16x8*)&Bs[(wc + n2 * 16 + r16) * 72 + kofs];
#pragma unroll
      for (int m2 = 0; m2 < 4; ++m2)
#pragma unroll
        for (int n2 = 0; n2 < 4; ++n2)
          acc[m2][n2] = __builtin_amdgcn_mfma_f32_16x16x32_bf16(
              aF[m2], bF[n2], acc[m2][n2], 0, 0, 0);
    }
  }

  float sv[4], bv[4];
#pragma unroll
  for (int n2 = 0; n2 < 4; ++n2) {
    const int c = bn + wc + n2 * 16 + r16;
    sv[n2] = sc[c];
    bv[n2] = bi[c];
  }
#pragma unroll
  for (int m2 = 0; m2 < 4; ++m2) {
    const int row0 = bm + wr + m2 * 16 + g4 * 4;
#pragma unroll
    for (int n2 = 0; n2 < 4; ++n2) {
      const int c = bn + wc + n2 * 16 + r16;
      float* op = out + (long long)row0 * NDIM + c;
#pragma unroll
      for (int r = 0; r < 4; ++r)
        op[(long long)r * NDIM] = acc[m2][n2][r] * sv[n2] + bv[n2];
    }
  }
}

extern "C" void kernel_launch(void* const* d_in, const int* in_sizes, int n_in,
                              void* d_out, int out_size, void* d_ws, size_t ws_size,
                              hipStream_t stream) {
  const float* A = (const float*)d_in[0];
  const int* W = (const int*)d_in[1];
  const float* sc = (const float*)d_in[2];
  const float* bi = (const float*)d_in[3];
  float* out = (float*)d_out;

  const size_t needA = (size_t)MDIM * KDIM;          // int8: 32 MB
  const size_t needW = (size_t)NDIM * KDIM;          // int8: 64 MB
  const size_t offS = needA + needW;                 // 96 MB
  const size_t need = offS + (size_t)MDIM * 4;       // + sA

  if (d_ws != nullptr && ws_size >= need) {
    signed char* Ab = (signed char*)d_ws;
    signed char* Wb = (signed char*)d_ws + needA;
    float* sA = (float*)((char*)d_ws + offS);
    cvt_a_q8<<<8192, 256, 0, stream>>>(A, Ab, sA);
    cvt_w_q8<<<4096, 256, 0, stream>>>(W, Wb);
    gemm_i8_v14<<<2048, 512, 0, stream>>>(Ab, Wb, sA, sc, bi, out);
  } else {
    gemm_inline<<<8192, 256, 0, stream>>>(A, W, sc, bi, out);
  }
}